// Round 14
// baseline (636.795 us; speedup 1.0000x reference)
//
#include <hip/hip_runtime.h>
#include <hip/hip_bf16.h>

typedef short bf16x8 __attribute__((ext_vector_type(8)));
typedef float f32x4 __attribute__((ext_vector_type(4)));

#define CCH 512
#define NPIX 4096
#define NB 4

__device__ inline unsigned short f2bf(float f) {
  union { __hip_bfloat16 h; unsigned short u; } cv;
  cv.h = __float2bfloat16(f);
  return cv.u;
}

#define GLD16(gp, lp) __builtin_amdgcn_global_load_lds( \
    (const __attribute__((address_space(1))) unsigned int*)(gp), \
    (__attribute__((address_space(3))) unsigned int*)(lp), 16, 0, 0)

// ---------------- weight fp32 -> bf16 cast ----------------
__global__ __launch_bounds__(256) void cast_weights_k(
    const float* __restrict__ w0, const float* __restrict__ w1,
    const float* __restrict__ w2, const float* __restrict__ w3,
    unsigned short* __restrict__ out) {
  int z = blockIdx.y;
  const float* src = (z == 0) ? w0 : (z == 1) ? w1 : (z == 2) ? w2 : w3;
  long i = (long)blockIdx.x * 256 + threadIdx.x;
  out[(long)z * CCH * CCH + i] = f2bf(src[i]);
}

// ---------------- concat bq,bk -> bqk[1024] ----------------
__global__ __launch_bounds__(256) void bias_concat_k(
    const float* __restrict__ bq, const float* __restrict__ bk,
    float* __restrict__ bqk) {
  int i = blockIdx.x * 256 + threadIdx.x;
  bqk[i] = (i < CCH) ? bq[i] : bk[i - CCH];
}

// ---------------- zero the softmax row-sum accumulator ----------------
__global__ __launch_bounds__(256) void zero_l_k(float* __restrict__ lsum) {
  int i = (blockIdx.x * 256 + threadIdx.x) * 4;
  *(float4*)(lsum + i) = make_float4(0.f, 0.f, 0.f, 0.f);
}

// ---------------- instance-norm stats: one block per (b,c) plane ----------------
__global__ __launch_bounds__(256) void stats_k(const float* __restrict__ x,
                                               float* __restrict__ stats) {
  long plane = blockIdx.x;
  const float4* p = (const float4*)(x + plane * NPIX);
  int t = threadIdx.x;
  float s = 0.f, q = 0.f;
  for (int c = 0; c < 4; c++) {
    float4 v = p[c * 256 + t];
    s += v.x + v.y + v.z + v.w;
    q += v.x * v.x + v.y * v.y + v.z * v.z + v.w * v.w;
  }
  for (int off = 32; off; off >>= 1) { s += __shfl_xor(s, off); q += __shfl_xor(q, off); }
  __shared__ float rs[4], rq[4];
  int w = t >> 6;
  if ((t & 63) == 0) { rs[w] = s; rq[w] = q; }
  __syncthreads();
  if (t == 0) {
    s = rs[0] + rs[1] + rs[2] + rs[3];
    q = rq[0] + rq[1] + rq[2] + rq[3];
    float mu = s * (1.f / NPIX);
    float var = q * (1.f / NPIX) - mu * mu;
    stats[2 * plane] = mu;
    stats[2 * plane + 1] = rsqrtf(var + 1e-5f);
  }
}

// ---------------- normalize + transpose: x[b][c][i] -> hnT[b][i][c] bf16 ----------------
__global__ __launch_bounds__(256) void norm_t_k(const float* __restrict__ x,
                                                const float* __restrict__ stats,
                                                unsigned short* __restrict__ hnT) {
  int b = blockIdx.z;
  int c0 = blockIdx.y * 32, i0 = blockIdx.x * 32;
  __shared__ float tile[32][33];
  int t = threadIdx.x;
  int il = t & 31, cl = t >> 5;  // cl in 0..7
  for (int r = 0; r < 4; r++) {
    int c = c0 + cl + r * 8;
    long pl = (long)b * CCH + c;
    float mu = stats[2 * pl], rsg = stats[2 * pl + 1];
    tile[cl + r * 8][il] = (x[pl * NPIX + i0 + il] - mu) * rsg;
  }
  __syncthreads();
  for (int r = 0; r < 4; r++) {
    int i = i0 + cl + r * 8;
    hnT[((long)b * NPIX + i) * CCH + c0 + il] = f2bf(tile[il][cl + r * 8]);
  }
}

// ========== persistent 8-phase 256x256 S-kernel (4 n-tiles per block) =======
// E[b][i][j] = exp2(scale * Q.K^T), lsum[b][i] += row sums. K=512 fixed.
// Grid (4,16,4) = 256 blocks = 1/CU. Each block computes 4 consecutive 256-wide
// n-tiles with a CONTINUOUS pipeline: groups 6,7 of tile tt stage tiles 0,1 of
// tile tt+1 (B pointer advanced 256 rows, A restaged, same slot parity), and
// tt's epilogue (exp/stores/atomics, ~2000cy, no LDS) runs between groups —
// covering tt+1's staging latency. Ledger identical to r13 (proven): per group,
// P1 stages A0+B0 (freed P0), P2 stages B1 (freed P1), P3 stages A1 (freed P2);
// P3's vmcnt(8) = this group's 8 in-flight loads -> validates prior tile fully.
#define SHT(sl, ha, h, kk, gBp) do {                                         \
    const unsigned short* g_ = ((ha) ? (gBp) : gA) + (long)(kk) * 64 +       \
                               (long)(2 * (h)) * 65536;                      \
    char* l_ = (char*)LDSu + (sl) * 65536 + (ha) * 32768 + (2 * (h)) * 8192  \
               + t * 16;                                                     \
    GLD16(g_, l_);                                                           \
    GLD16(g_ + 65536, l_ + 8192);                                            \
  } while (0)

#define READ_A(sl, half) do {                                                \
    const unsigned short* sa_ = LDSu + (sl) * 32768;                         \
    _Pragma("unroll") for (int mm = 0; mm < 4; mm++) {                       \
      int row = ((half) * 4 + mm) * 32 + wr * 16 + fr;                       \
      a_[mm][0] = *(const bf16x8*)(sa_ + row * 64 + o0_);                    \
      a_[mm][1] = *(const bf16x8*)(sa_ + row * 64 + o1_);                    \
    }                                                                        \
  } while (0)

#define READ_B(sl, half, dst) do {                                           \
    const unsigned short* sb_ = LDSu + (sl) * 32768 + 16384;                 \
    _Pragma("unroll") for (int nn = 0; nn < 2; nn++) {                       \
      int row = ((half) * 2 + nn) * 64 + wc * 16 + fr;                       \
      dst[nn][0] = *(const bf16x8*)(sb_ + row * 64 + o0_);                   \
      dst[nn][1] = *(const bf16x8*)(sb_ + row * 64 + o1_);                   \
    }                                                                        \
  } while (0)

#define MF(qm, qn, bb)                                                       \
    _Pragma("unroll") for (int mm = 0; mm < 4; mm++)                         \
      _Pragma("unroll") for (int nn = 0; nn < 2; nn++) {                     \
        acc[(qm) * 4 + mm][(qn) * 2 + nn] =                                  \
            __builtin_amdgcn_mfma_f32_16x16x32_bf16(                         \
                a_[mm][0], bb[nn][0], acc[(qm) * 4 + mm][(qn) * 2 + nn],     \
                0, 0, 0);                                                    \
        acc[(qm) * 4 + mm][(qn) * 2 + nn] =                                  \
            __builtin_amdgcn_mfma_f32_16x16x32_bf16(                         \
                a_[mm][1], bb[nn][1], acc[(qm) * 4 + mm][(qn) * 2 + nn],     \
                0, 0, 0);                                                    \
      }

#define PHASE(VN, SSTMT, RSTMT, MSTMT) do {                                  \
    SSTMT;                                                                   \
    RSTMT;                                                                   \
    if ((VN) == 8) asm volatile("s_waitcnt vmcnt(8)" ::: "memory");          \
    else if ((VN) == 0) asm volatile("s_waitcnt vmcnt(0)" ::: "memory");     \
    __builtin_amdgcn_s_barrier();                                            \
    asm volatile("s_waitcnt lgkmcnt(0)" ::: "memory");                       \
    __builtin_amdgcn_sched_barrier(0);                                       \
    __builtin_amdgcn_s_setprio(1);                                           \
    MSTMT;                                                                   \
    __builtin_amdgcn_s_setprio(0);                                           \
    __builtin_amdgcn_sched_barrier(0);                                       \
    __builtin_amdgcn_s_barrier();                                            \
  } while (0)

// staged group: consume slot sl, stage k-tile kk (A from gA, B from gBp)
#define GROUP_S(sl, kk, gBp)                                                 \
    PHASE(-1, (void)0, { READ_A(sl, 0); READ_B(sl, 0, b0_); }, MF(0, 0, b0_)); \
    PHASE(-1, { SHT(sl, 0, 0, kk, gBp); SHT(sl, 1, 0, kk, gBp); },           \
          READ_B(sl, 1, b1_), MF(0, 1, b1_));                                \
    PHASE(-1, SHT(sl, 1, 1, kk, gBp), READ_A(sl, 1), MF(1, 1, b1_));         \
    PHASE(8, SHT(sl, 0, 1, kk, gBp), (void)0, MF(1, 0, b0_))

// unstaged group: VN3 = vmcnt at P3 (0 to validate the final tile, -1 none)
#define GROUP_N(sl, VN3)                                                     \
    PHASE(-1, (void)0, { READ_A(sl, 0); READ_B(sl, 0, b0_); }, MF(0, 0, b0_)); \
    PHASE(-1, (void)0, READ_B(sl, 1, b1_), MF(0, 1, b1_));                   \
    PHASE(-1, (void)0, READ_A(sl, 1), MF(1, 1, b1_));                        \
    PHASE(VN3, (void)0, (void)0, MF(1, 0, b0_))

__global__ __launch_bounds__(512, 2) void gemm8p_s_k(
    const unsigned short* __restrict__ A,   // Q rows [i][1024]
    const unsigned short* __restrict__ B,   // K rows (A + 512)
    unsigned short* __restrict__ C,         // E bf16 [i][4096]
    float* __restrict__ lsum, float scale) {
  const int z = blockIdx.z;
  const long SLAB2 = (long)NPIX * 1024;
  const long SLABP = (long)NPIX * NPIX;
  A += z * SLAB2;
  B += z * SLAB2;
  // region-mapped block swizzle: XCD xcd owns by in {2*xcd, 2*xcd+1}, all bx
  // (blocks sharing a Q-tile land on the same XCD's L2)
  int s = blockIdx.x + 4 * blockIdx.y;  // 0..63, 64%8==0 per z -> phase stable
  int xcd = s & 7, idx = s >> 3;
  int bx = idx & 3, by = xcd * 2 + (idx >> 2);
  const int m0 = by * 256, n0b = bx * 1024;
  const int t = threadIdx.x;
  const int lane = t & 63, w = t >> 6;
  const int wr = w >> 2, wc = w & 3;
  const int fr = lane & 15, fq = lane >> 4;
  const int chx = fr & 7;
  const int o0_ = (fq ^ chx) * 8, o1_ = ((fq + 4) ^ chx) * 8;

  __shared__ __align__(16) unsigned short LDSu[2 * 32768];  // 128 KB

  f32x4 acc[8][4] = {};
  bf16x8 a_[4][2], b0_[2][2], b1_[2][2];

  const int srow = t >> 3;                        // 0..63
  const int scol = ((t & 7) ^ (srow & 7)) * 8;    // pre-swizzled source col
  const unsigned short* gA = A + (long)(m0 + srow) * 1024 + scol;
  const unsigned short* gB = B + (long)(n0b + srow) * 1024 + scol;
  const long BSTR = (long)256 * 1024;             // B advance per n-tile

  // prologue: tile0 k0,k1 -> slots 0,1 (16 loads); vmcnt(8) validates k0
  SHT(0, 0, 0, 0, gB); SHT(0, 1, 0, 0, gB); SHT(0, 0, 1, 0, gB); SHT(0, 1, 1, 0, gB);
  SHT(1, 0, 0, 1, gB); SHT(1, 1, 0, 1, gB); SHT(1, 0, 1, 1, gB); SHT(1, 1, 1, 1, gB);
  asm volatile("s_waitcnt vmcnt(8)" ::: "memory");
  __builtin_amdgcn_s_barrier();

  for (int tt = 0; tt < 4; ++tt) {
    const unsigned short* gBc = gB + (long)tt * BSTR;
    if (tt < 3) {
      const unsigned short* gBn = gBc + BSTR;
      GROUP_S(0, 2, gBc); GROUP_S(1, 3, gBc);
      GROUP_S(0, 4, gBc); GROUP_S(1, 5, gBc);
      GROUP_S(0, 6, gBc); GROUP_S(1, 7, gBc);
      GROUP_S(0, 0, gBn); GROUP_S(1, 1, gBn);   // g6,g7: stage next tile k0,k1
    } else {
      GROUP_S(0, 2, gBc); GROUP_S(1, 3, gBc);
      GROUP_S(0, 4, gBc); GROUP_S(1, 5, gBc);
      GROUP_S(0, 6, gBc); GROUP_S(1, 7, gBc);
      GROUP_N(0, 0); GROUP_N(1, -1);            // drain
    }
    // epilogue for tile tt (no LDS; overlaps next tile's staging latency)
    const int n0 = n0b + tt * 256;
    float rsum[8][4];
    for (int i = 0; i < 8; i++)
      for (int r = 0; r < 4; r++) rsum[i][r] = 0.f;
    for (int i = 0; i < 8; i++) {
      int mg = m0 + i * 32 + wr * 16 + fq * 4;
      for (int j = 0; j < 4; j++) {
        int ng = n0 + j * 64 + wc * 16 + fr;
        for (int r = 0; r < 4; r++) {
          float v = exp2f(acc[i][j][r] * scale);
          rsum[i][r] += v;
          C[z * SLABP + (long)(mg + r) * 4096 + ng] = f2bf(v);
        }
      }
    }
    for (int i = 0; i < 8; i++)
      for (int r = 0; r < 4; r++) {
        float ss = rsum[i][r];
        ss += __shfl_xor(ss, 1);
        ss += __shfl_xor(ss, 2);
        ss += __shfl_xor(ss, 4);
        ss += __shfl_xor(ss, 8);
        if (fr == 0)
          atomicAdd(&lsum[z * NPIX + m0 + i * 32 + wr * 16 + fq * 4 + r], ss);
      }
    if (tt < 3) {
      f32x4 zz = {0.f, 0.f, 0.f, 0.f};
      for (int i = 0; i < 8; i++)
        for (int j = 0; j < 4; j++) acc[i][j] = zz;
    }
  }
}
#undef SHT
#undef READ_A
#undef READ_B
#undef MF
#undef PHASE
#undef GROUP_S
#undef GROUP_N

// ---------------- generic bf16 gemm_bt (r6 core + XCD swizzle, r10-proven) ----------------
template <int XCDX, int OUTF32, int BIASM, bool RESID, bool SCALE, bool EXPSUM, bool ROWSCALE>
__global__ __launch_bounds__(256) void gemm_bt_k(
    const unsigned short* __restrict__ A, const unsigned short* __restrict__ B,
    void* __restrict__ Cv, const float* __restrict__ bias,
    const float* __restrict__ resid, float* __restrict__ lsum,
    int K, int lda, int ldb, int ldc,
    long sA, long sB, long sC, float scale) {
  int z = blockIdx.z;
  A += z * sA;
  B += z * sB;

  int bx = blockIdx.x, by = blockIdx.y;
  if (XCDX > 0) {
    int s = blockIdx.x + gridDim.x * blockIdx.y;
    int xcd = s & 7, idx = s >> 3;
    int rw = gridDim.x / XCDX;
    int rh = (gridDim.y * XCDX) >> 3;
    int rx0 = (xcd % XCDX) * rw, ry0 = (xcd / XCDX) * rh;
    bx = rx0 + idx % rw;
    by = ry0 + idx / rw;
  }
  const int n0 = bx * 128, m0 = by * 128;

  const int t = threadIdx.x;
  const int lane = t & 63, w = t >> 6;
  const int wr = w >> 1, wc = w & 1;

  __shared__ __align__(16) unsigned short As[128 * 64];
  __shared__ __align__(16) unsigned short Bs[128 * 64];

  f32x4 acc[4][4] = {};

  const int srow = t >> 3;
  const int scol = (((t & 7) ^ (srow & 7)) * 8);
  const unsigned short* ga = A + (long)(m0 + srow) * lda + scol;
  const unsigned short* gb = B + (long)(n0 + srow) * ldb + scol;
  char* lA = (char*)As + t * 16;
  char* lB = (char*)Bs + t * 16;
  const long stpa = (long)32 * lda;
  const long stpb = (long)32 * ldb;

  const int fr = lane & 15, fq = lane >> 4;
  const int chx = fr & 7;
  const unsigned short* rA = As + (wr * 64 + fr) * 64;
  const unsigned short* rB = Bs + (wc * 64 + fr) * 64;

  const int nkt = K >> 6;
  for (int kt = 0; kt < nkt; kt++) {
    const unsigned short* gak = ga + (long)kt * 64;
    const unsigned short* gbk = gb + (long)kt * 64;
    GLD16(gak, lA);
    GLD16(gak + stpa, lA + 4096);
    GLD16(gak + 2 * stpa, lA + 8192);
    GLD16(gak + 3 * stpa, lA + 12288);
    GLD16(gbk, lB);
    GLD16(gbk + stpb, lB + 4096);
    GLD16(gbk + 2 * stpb, lB + 8192);
    GLD16(gbk + 3 * stpb, lB + 12288);
    __syncthreads();
    for (int kk = 0; kk < 2; kk++) {
      const int offA = ((fq + kk * 4) ^ chx) * 8;
      bf16x8 af[4], bfr[4];
      for (int i = 0; i < 4; i++) af[i] = *(const bf16x8*)(rA + i * 1024 + offA);
      for (int i = 0; i < 4; i++) bfr[i] = *(const bf16x8*)(rB + i * 1024 + offA);
      for (int i = 0; i < 4; i++)
        for (int j = 0; j < 4; j++)
          acc[i][j] = __builtin_amdgcn_mfma_f32_16x16x32_bf16(af[i], bfr[j], acc[i][j], 0, 0, 0);
    }
    __syncthreads();
  }

  if (OUTF32) {
    float* Cf = (float*)Cv;
    for (int i = 0; i < 4; i++) {
      int mg = m0 + wr * 64 + i * 16 + fq * 4;
      for (int j = 0; j < 4; j++) {
        int ng = n0 + wc * 64 + j * 16 + fr;
        for (int r = 0; r < 4; r++) {
          float v = acc[i][j][r];
          if (SCALE) v *= scale;
          int m = mg + r;
          if (BIASM == 1) v += bias[m];
          else if (BIASM == 2) v += bias[ng];
          long off = z * sC + (long)m * ldc + ng;
          if (RESID) v += resid[off];
          Cf[off] = v;
        }
      }
    }
  } else {
    float linv[4][4];
    if (ROWSCALE) {
      for (int i = 0; i < 4; i++)
        for (int r = 0; r < 4; r++)
          linv[i][r] = 1.f / lsum[z * NPIX + m0 + wr * 64 + i * 16 + fq * 4 + r];
    }
    float rsum[4][4];
    if (EXPSUM) {
      for (int i = 0; i < 4; i++)
        for (int r = 0; r < 4; r++) rsum[i][r] = 0.f;
    }
    unsigned short* Cb = (unsigned short*)Cv;
    for (int i = 0; i < 4; i++) {
      int mg = m0 + wr * 64 + i * 16 + fq * 4;
      for (int j = 0; j < 4; j++) {
        int ng = n0 + wc * 64 + j * 16 + fr;
        for (int r = 0; r < 4; r++) {
          float v = acc[i][j][r];
          if (SCALE) v *= scale;
          if (BIASM == 1) v += bias[mg + r];
          else if (BIASM == 2) v += bias[ng];
          if (EXPSUM) { v = exp2f(v); rsum[i][r] += v; }
          if (ROWSCALE) v *= linv[i][r];
          Cb[z * sC + (long)(mg + r) * ldc + ng] = f2bf(v);
        }
      }
    }
    if (EXPSUM) {
      for (int i = 0; i < 4; i++)
        for (int r = 0; r < 4; r++) {
          float s = rsum[i][r];
          s += __shfl_xor(s, 1);
          s += __shfl_xor(s, 2);
          s += __shfl_xor(s, 4);
          s += __shfl_xor(s, 8);
          if (fr == 0)
            atomicAdd(&lsum[z * NPIX + m0 + wr * 64 + i * 16 + fq * 4 + r], s);
        }
    }
  }
}

extern "C" void kernel_launch(void* const* d_in, const int* in_sizes, int n_in,
                              void* d_out, int out_size, void* d_ws, size_t ws_size,
                              hipStream_t stream) {
  const float* x  = (const float*)d_in[0];
  const float* wq = (const float*)d_in[1];
  const float* bq = (const float*)d_in[2];
  const float* wk = (const float*)d_in[3];
  const float* bk = (const float*)d_in[4];
  const float* wv = (const float*)d_in[5];
  const float* bv = (const float*)d_in[6];
  const float* wp = (const float*)d_in[7];
  const float* bp = (const float*)d_in[8];

  char* ws = (char*)d_ws;
  const long SLAB = (long)NPIX * CCH;
  const long SLAB2 = (long)NPIX * 1024;
  const long SLABP = (long)NPIX * NPIX;

  float* stats = (float*)ws;
  float* bqk = (float*)(ws + (32l << 10));
  float* lsum = (float*)(ws + (64l << 10));
  unsigned short* wbf = (unsigned short*)(ws + (192l << 10));
  unsigned short* hnT = (unsigned short*)(ws + (192l << 10) + (1l << 21));
  unsigned short* QKt = hnT + 4 * SLAB;
  unsigned short* V   = QKt + 4 * SLAB2;
  unsigned short* Ot  = V + 4 * SLAB;
  unsigned short* S4  = Ot + 4 * SLAB;

  unsigned short* wv_bf = wbf + 2 * 262144;
  unsigned short* wp_bf = wbf + 3 * 262144;

  cast_weights_k<<<dim3(1024, 4, 1), 256, 0, stream>>>(wq, wk, wv, wp, wbf);
  bias_concat_k<<<dim3(4, 1, 1), 256, 0, stream>>>(bq, bk, bqk);
  zero_l_k<<<dim3(16, 1, 1), 256, 0, stream>>>(lsum);
  stats_k<<<dim3(NB * CCH, 1, 1), 256, 0, stream>>>(x, stats);
  norm_t_k<<<dim3(128, 16, 4), 256, 0, stream>>>(x, stats, hnT);

  // QKt[b][i][n] = hnT[b] . [wq;wk]^T + bqk
  gemm_bt_k<1, 0, 2, false, false, false, false><<<dim3(8, 32, 4), 256, 0, stream>>>(
      hnT, wbf, QKt, bqk, nullptr, nullptr, 512, 512, 512, 1024, SLAB, 0, SLAB2, 1.f);
  // V[b][o][j] = Wv . hnT[b]^T + bv
  gemm_bt_k<2, 0, 1, false, false, false, false><<<dim3(32, 4, 4), 256, 0, stream>>>(
      wv_bf, hnT, V, bv, nullptr, nullptr, 512, 512, 512, 4096, 0, SLAB, SLAB, 1.f);

  // scale = (1/sqrt(512)) * log2(e)
  const float isc2 = 0.06375871387551278f;
  // E = exp(Q.K^T/sqrt(C)) via persistent 8-phase 256^2 kernel (4 tiles/block)
  gemm8p_s_k<<<dim3(4, 16, 4), 512, 0, stream>>>(QKt, QKt + 512, S4, lsum, isc2);
  // Ot[b][i][c] = (E[b] . V[b]^T) / lsum[b][i]
  gemm_bt_k<1, 0, 0, false, false, false, true><<<dim3(4, 32, 4), 256, 0, stream>>>(
      S4, V, Ot, nullptr, nullptr, lsum, 4096, 4096, 4096, 512, SLABP, SLAB, SLAB, 1.f);
  // out[b][o][i] = x + Wp . Ot[b]^T + bp
  gemm_bt_k<2, 1, 1, true, false, false, false><<<dim3(32, 4, 4), 256, 0, stream>>>(
      wp_bf, Ot, d_out, bp, x, nullptr, 512, 512, 512, 4096, 0, SLAB, SLAB, 1.f);
}

// Round 15
// 294.103 us; speedup vs baseline: 2.1652x; 2.1652x over previous
//
#include <hip/hip_runtime.h>
#include <hip/hip_bf16.h>

typedef short bf16x8 __attribute__((ext_vector_type(8)));
typedef float f32x4 __attribute__((ext_vector_type(4)));

#define CCH 512
#define NPIX 4096
#define NB 4

__device__ inline unsigned short f2bf(float f) {
  union { __hip_bfloat16 h; unsigned short u; } cv;
  cv.h = __float2bfloat16(f);
  return cv.u;
}

#define GLD16(gp, lp) __builtin_amdgcn_global_load_lds( \
    (const __attribute__((address_space(1))) unsigned int*)(gp), \
    (__attribute__((address_space(3))) unsigned int*)(lp), 16, 0, 0)

// ---------------- weight fp32 -> bf16 cast ----------------
__global__ __launch_bounds__(256) void cast_weights_k(
    const float* __restrict__ w0, const float* __restrict__ w1,
    const float* __restrict__ w2, const float* __restrict__ w3,
    unsigned short* __restrict__ out) {
  int z = blockIdx.y;
  const float* src = (z == 0) ? w0 : (z == 1) ? w1 : (z == 2) ? w2 : w3;
  long i = (long)blockIdx.x * 256 + threadIdx.x;
  out[(long)z * CCH * CCH + i] = f2bf(src[i]);
}

// ---------------- concat bq,bk -> bqk[1024] ----------------
__global__ __launch_bounds__(256) void bias_concat_k(
    const float* __restrict__ bq, const float* __restrict__ bk,
    float* __restrict__ bqk) {
  int i = blockIdx.x * 256 + threadIdx.x;
  bqk[i] = (i < CCH) ? bq[i] : bk[i - CCH];
}

// ---------------- zero the softmax row-sum accumulator ----------------
__global__ __launch_bounds__(256) void zero_l_k(float* __restrict__ lsum) {
  int i = (blockIdx.x * 256 + threadIdx.x) * 4;
  *(float4*)(lsum + i) = make_float4(0.f, 0.f, 0.f, 0.f);
}

// ---------------- instance-norm stats: one block per (b,c) plane ----------------
__global__ __launch_bounds__(256) void stats_k(const float* __restrict__ x,
                                               float* __restrict__ stats) {
  long plane = blockIdx.x;
  const float4* p = (const float4*)(x + plane * NPIX);
  int t = threadIdx.x;
  float s = 0.f, q = 0.f;
  for (int c = 0; c < 4; c++) {
    float4 v = p[c * 256 + t];
    s += v.x + v.y + v.z + v.w;
    q += v.x * v.x + v.y * v.y + v.z * v.z + v.w * v.w;
  }
  for (int off = 32; off; off >>= 1) { s += __shfl_xor(s, off); q += __shfl_xor(q, off); }
  __shared__ float rs[4], rq[4];
  int w = t >> 6;
  if ((t & 63) == 0) { rs[w] = s; rq[w] = q; }
  __syncthreads();
  if (t == 0) {
    s = rs[0] + rs[1] + rs[2] + rs[3];
    q = rq[0] + rq[1] + rq[2] + rq[3];
    float mu = s * (1.f / NPIX);
    float var = q * (1.f / NPIX) - mu * mu;
    stats[2 * plane] = mu;
    stats[2 * plane + 1] = rsqrtf(var + 1e-5f);
  }
}

// ---------------- normalize + transpose: x[b][c][i] -> hnT[b][i][c] bf16 ----------------
__global__ __launch_bounds__(256) void norm_t_k(const float* __restrict__ x,
                                                const float* __restrict__ stats,
                                                unsigned short* __restrict__ hnT) {
  int b = blockIdx.z;
  int c0 = blockIdx.y * 32, i0 = blockIdx.x * 32;
  __shared__ float tile[32][33];
  int t = threadIdx.x;
  int il = t & 31, cl = t >> 5;  // cl in 0..7
  for (int r = 0; r < 4; r++) {
    int c = c0 + cl + r * 8;
    long pl = (long)b * CCH + c;
    float mu = stats[2 * pl], rsg = stats[2 * pl + 1];
    tile[cl + r * 8][il] = (x[pl * NPIX + i0 + il] - mu) * rsg;
  }
  __syncthreads();
  for (int r = 0; r < 4; r++) {
    int i = i0 + cl + r * 8;
    hnT[((long)b * NPIX + i) * CCH + c0 + il] = f2bf(tile[il][cl + r * 8]);
  }
}

// ================= 8-phase 256x256 S-kernel (r13, proven 119us) =============
#define SH(sl, ha, h, kt) do {                                               \
    const unsigned short* g_ = ((ha) ? gB : gA) + (long)(kt) * 64 +          \
                               (long)(2 * (h)) * 65536;                      \
    char* l_ = (char*)LDSu + (sl) * 65536 + (ha) * 32768 + (2 * (h)) * 8192  \
               + t * 16;                                                     \
    GLD16(g_, l_);                                                           \
    GLD16(g_ + 65536, l_ + 8192);                                            \
  } while (0)

#define READ_A(sl, half) do {                                                \
    const unsigned short* sa_ = LDSu + (sl) * 32768;                         \
    _Pragma("unroll") for (int mm = 0; mm < 4; mm++) {                       \
      int row = ((half) * 4 + mm) * 32 + wr * 16 + fr;                       \
      a_[mm][0] = *(const bf16x8*)(sa_ + row * 64 + o0_);                    \
      a_[mm][1] = *(const bf16x8*)(sa_ + row * 64 + o1_);                    \
    }                                                                        \
  } while (0)

#define READ_B(sl, half, dst) do {                                           \
    const unsigned short* sb_ = LDSu + (sl) * 32768 + 16384;                 \
    _Pragma("unroll") for (int nn = 0; nn < 2; nn++) {                       \
      int row = ((half) * 2 + nn) * 64 + wc * 16 + fr;                       \
      dst[nn][0] = *(const bf16x8*)(sb_ + row * 64 + o0_);                   \
      dst[nn][1] = *(const bf16x8*)(sb_ + row * 64 + o1_);                   \
    }                                                                        \
  } while (0)

#define MF(qm, qn, bb)                                                       \
    _Pragma("unroll") for (int mm = 0; mm < 4; mm++)                         \
      _Pragma("unroll") for (int nn = 0; nn < 2; nn++) {                     \
        acc[(qm) * 4 + mm][(qn) * 2 + nn] =                                  \
            __builtin_amdgcn_mfma_f32_16x16x32_bf16(                         \
                a_[mm][0], bb[nn][0], acc[(qm) * 4 + mm][(qn) * 2 + nn],     \
                0, 0, 0);                                                    \
        acc[(qm) * 4 + mm][(qn) * 2 + nn] =                                  \
            __builtin_amdgcn_mfma_f32_16x16x32_bf16(                         \
                a_[mm][1], bb[nn][1], acc[(qm) * 4 + mm][(qn) * 2 + nn],     \
                0, 0, 0);                                                    \
      }

#define PHASE(VN, SSTMT, RSTMT, MSTMT) do {                                  \
    SSTMT;                                                                   \
    RSTMT;                                                                   \
    if ((VN) == 8) asm volatile("s_waitcnt vmcnt(8)" ::: "memory");          \
    else if ((VN) == 0) asm volatile("s_waitcnt vmcnt(0)" ::: "memory");     \
    __builtin_amdgcn_s_barrier();                                            \
    asm volatile("s_waitcnt lgkmcnt(0)" ::: "memory");                       \
    __builtin_amdgcn_sched_barrier(0);                                       \
    __builtin_amdgcn_s_setprio(1);                                           \
    MSTMT;                                                                   \
    __builtin_amdgcn_s_setprio(0);                                           \
    __builtin_amdgcn_sched_barrier(0);                                       \
    __builtin_amdgcn_s_barrier();                                            \
  } while (0)

#define GROUP_S(sl, tn)                                                      \
    PHASE(-1, (void)0, { READ_A(sl, 0); READ_B(sl, 0, b0_); }, MF(0, 0, b0_)); \
    PHASE(-1, { SH(sl, 0, 0, tn); SH(sl, 1, 0, tn); },                       \
          READ_B(sl, 1, b1_), MF(0, 1, b1_));                                \
    PHASE(-1, SH(sl, 1, 1, tn), READ_A(sl, 1), MF(1, 1, b1_));               \
    PHASE(8, SH(sl, 0, 1, tn), (void)0, MF(1, 0, b0_))

#define GROUP_N(sl, VN3)                                                     \
    PHASE(-1, (void)0, { READ_A(sl, 0); READ_B(sl, 0, b0_); }, MF(0, 0, b0_)); \
    PHASE(-1, (void)0, READ_B(sl, 1, b1_), MF(0, 1, b1_));                   \
    PHASE(-1, (void)0, READ_A(sl, 1), MF(1, 1, b1_));                        \
    PHASE(VN3, (void)0, (void)0, MF(1, 0, b0_))

__global__ __launch_bounds__(512, 2) void gemm8p_s_k(
    const unsigned short* __restrict__ A,   // Q rows [i][1024]
    const unsigned short* __restrict__ B,   // K rows (A + 512)
    unsigned short* __restrict__ C,         // E bf16 [i][4096]
    float* __restrict__ lsum, float scale) {
  const int z = blockIdx.z;
  const long SLAB2 = (long)NPIX * 1024;
  const long SLABP = (long)NPIX * NPIX;
  A += z * SLAB2;
  B += z * SLAB2;
  const int m0 = blockIdx.y * 256, n0 = blockIdx.x * 256;
  const int t = threadIdx.x;
  const int lane = t & 63, w = t >> 6;
  const int wr = w >> 2, wc = w & 3;
  const int fr = lane & 15, fq = lane >> 4;
  const int chx = fr & 7;
  const int o0_ = (fq ^ chx) * 8, o1_ = ((fq + 4) ^ chx) * 8;

  __shared__ __align__(16) unsigned short LDSu[2 * 32768];  // 128 KB

  f32x4 acc[8][4] = {};
  bf16x8 a_[4][2], b0_[2][2], b1_[2][2];

  const int srow = t >> 3;                        // 0..63
  const int scol = ((t & 7) ^ (srow & 7)) * 8;    // pre-swizzled source col
  const unsigned short* gA = A + (long)(m0 + srow) * 1024 + scol;
  const unsigned short* gB = B + (long)(n0 + srow) * 1024 + scol;

  SH(0, 0, 0, 0); SH(0, 1, 0, 0); SH(0, 0, 1, 0); SH(0, 1, 1, 0);
  SH(1, 0, 0, 1); SH(1, 1, 0, 1); SH(1, 0, 1, 1); SH(1, 1, 1, 1);
  asm volatile("s_waitcnt vmcnt(8)" ::: "memory");
  __builtin_amdgcn_s_barrier();

  GROUP_S(0, 2); GROUP_S(1, 3);
  GROUP_S(0, 4); GROUP_S(1, 5);
  GROUP_S(0, 6); GROUP_S(1, 7);
  GROUP_N(0, 0);
  GROUP_N(1, -1);

  float rsum[8][4];
  for (int i = 0; i < 8; i++)
    for (int r = 0; r < 4; r++) rsum[i][r] = 0.f;
  for (int i = 0; i < 8; i++) {
    int mg = m0 + i * 32 + wr * 16 + fq * 4;
    for (int j = 0; j < 4; j++) {
      int ng = n0 + j * 64 + wc * 16 + fr;
      for (int r = 0; r < 4; r++) {
        float v = exp2f(acc[i][j][r] * scale);
        rsum[i][r] += v;
        C[z * SLABP + (long)(mg + r) * 4096 + ng] = f2bf(v);
      }
    }
  }
  for (int i = 0; i < 8; i++)
    for (int r = 0; r < 4; r++) {
      float s = rsum[i][r];
      s += __shfl_xor(s, 1);
      s += __shfl_xor(s, 2);
      s += __shfl_xor(s, 4);
      s += __shfl_xor(s, 8);
      if (fr == 0)
        atomicAdd(&lsum[z * NPIX + m0 + i * 32 + wr * 16 + fq * 4 + r], s);
    }
}
#undef SH
#undef READ_A
#undef READ_B
#undef MF
#undef PHASE
#undef GROUP_S
#undef GROUP_N

// ============ 8-phase 256x128 PV kernel: Ot = (E . V^T) / lsum ==============
// M=4096 (E rows), N=512 (channels), K=4096 -> 64 k-tiles: deep amortization.
// Tile 256m x 128n, 8 waves in 4(M) x 2(N): wave = 64 rows x 64 cols.
// Frags: m-frag i at rows i*64+wr*16 (i=0..3; half = i<2), n-frag j at cols
// j*32+wc*16 (j=0..3; half = j<2). 16 b128-reads vs 32 MFMA per wave/k-tile
// (DS ~512cy vs MFMA ~310cy per CU -> ~60% ceiling). LDS: A 2x32KB + B 2x16KB
// = 96 KB. Ledger (r13-proven shape): P1 stages A0+B0, P2 stages B1, P3 stages
// A1 + vmcnt(6) (= this group's 6 staged loads -> prior tile validated).
// Grid (4,16,4) = 256 blocks = 1/CU. Stores ONLY after final drain (r14 lesson:
// stores inside a counted-vmcnt pipeline corrupt the ledger).
#define SH_A(sl, h, kk) do {                                                 \
    const unsigned short* g_ = gA + (long)(kk) * 64 + (long)(2 * (h)) * 262144; \
    char* l_ = (char*)LDSu + (sl) * 32768 + (2 * (h)) * 8192 + t * 16;       \
    GLD16(g_, l_);                                                           \
    GLD16(g_ + 262144, l_ + 8192);                                           \
  } while (0)

#define SH_B(sl, h, kk) do {                                                 \
    const unsigned short* g_ = gB + (long)(kk) * 64 + (long)(h) * 262144;    \
    char* l_ = (char*)LDSu + 65536 + (sl) * 16384 + (h) * 8192 + t * 16;     \
    GLD16(g_, l_);                                                           \
  } while (0)

#define READ_PA(sl, half) do {                                               \
    const unsigned short* sa_ = LDSu + (sl) * 16384;                         \
    _Pragma("unroll") for (int mm = 0; mm < 2; mm++) {                       \
      int row = ((half) * 2 + mm) * 64 + wr * 16 + fr;                       \
      a_[mm][0] = *(const bf16x8*)(sa_ + row * 64 + o0_);                    \
      a_[mm][1] = *(const bf16x8*)(sa_ + row * 64 + o1_);                    \
    }                                                                        \
  } while (0)

#define READ_PB(sl, half, dst) do {                                          \
    const unsigned short* sb_ = LDSu + 32768 + (sl) * 8192;                  \
    _Pragma("unroll") for (int nn = 0; nn < 2; nn++) {                       \
      int row = ((half) * 2 + nn) * 32 + wc * 16 + fr;                       \
      dst[nn][0] = *(const bf16x8*)(sb_ + row * 64 + o0_);                   \
      dst[nn][1] = *(const bf16x8*)(sb_ + row * 64 + o1_);                   \
    }                                                                        \
  } while (0)

#define MF_P(qm, qn, bb)                                                     \
    _Pragma("unroll") for (int mm = 0; mm < 2; mm++)                         \
      _Pragma("unroll") for (int nn = 0; nn < 2; nn++) {                     \
        acc[(qm) * 2 + mm][(qn) * 2 + nn] =                                  \
            __builtin_amdgcn_mfma_f32_16x16x32_bf16(                         \
                a_[mm][0], bb[nn][0], acc[(qm) * 2 + mm][(qn) * 2 + nn],     \
                0, 0, 0);                                                    \
        acc[(qm) * 2 + mm][(qn) * 2 + nn] =                                  \
            __builtin_amdgcn_mfma_f32_16x16x32_bf16(                         \
                a_[mm][1], bb[nn][1], acc[(qm) * 2 + mm][(qn) * 2 + nn],     \
                0, 0, 0);                                                    \
      }

#define PHP(VN, SSTMT, RSTMT, MSTMT) do {                                    \
    SSTMT;                                                                   \
    RSTMT;                                                                   \
    if ((VN) == 6) asm volatile("s_waitcnt vmcnt(6)" ::: "memory");          \
    else if ((VN) == 0) asm volatile("s_waitcnt vmcnt(0)" ::: "memory");     \
    __builtin_amdgcn_s_barrier();                                            \
    asm volatile("s_waitcnt lgkmcnt(0)" ::: "memory");                       \
    __builtin_amdgcn_sched_barrier(0);                                       \
    __builtin_amdgcn_s_setprio(1);                                           \
    MSTMT;                                                                   \
    __builtin_amdgcn_s_setprio(0);                                           \
    __builtin_amdgcn_sched_barrier(0);                                       \
    __builtin_amdgcn_s_barrier();                                            \
  } while (0)

#define GROUP_PS(sl, kk)                                                     \
    PHP(-1, (void)0, { READ_PA(sl, 0); READ_PB(sl, 0, b0_); }, MF_P(0, 0, b0_)); \
    PHP(-1, { SH_A(sl, 0, kk); SH_B(sl, 0, kk); },                           \
        READ_PB(sl, 1, b1_), MF_P(0, 1, b1_));                               \
    PHP(-1, SH_B(sl, 1, kk), READ_PA(sl, 1), MF_P(1, 1, b1_));               \
    PHP(6, SH_A(sl, 1, kk), (void)0, MF_P(1, 0, b0_))

#define GROUP_PN(sl, VN3)                                                    \
    PHP(-1, (void)0, { READ_PA(sl, 0); READ_PB(sl, 0, b0_); }, MF_P(0, 0, b0_)); \
    PHP(-1, (void)0, READ_PB(sl, 1, b1_), MF_P(0, 1, b1_));                  \
    PHP(-1, (void)0, READ_PA(sl, 1), MF_P(1, 1, b1_));                       \
    PHP(VN3, (void)0, (void)0, MF_P(1, 0, b0_))

__global__ __launch_bounds__(512, 2) void gemm8p_pv_k(
    const unsigned short* __restrict__ A,   // E [i][4096]
    const unsigned short* __restrict__ B,   // V [o][4096]
    unsigned short* __restrict__ C,         // Ot bf16 [i][512]
    const float* __restrict__ lsum) {
  const int z = blockIdx.z;
  const long SLAB = (long)NPIX * CCH;
  const long SLABP = (long)NPIX * NPIX;
  A += z * SLABP;
  B += z * SLAB;
  const int m0 = blockIdx.y * 256, n0 = blockIdx.x * 128;
  const int t = threadIdx.x;
  const int lane = t & 63, w = t >> 6;
  const int wr = w >> 1, wc = w & 1;   // 4(M) x 2(N) wave grid
  const int fr = lane & 15, fq = lane >> 4;
  const int chx = fr & 7;
  const int o0_ = (fq ^ chx) * 8, o1_ = ((fq + 4) ^ chx) * 8;

  // [A slot0 32KB][A slot1 32KB][B slot0 16KB][B slot1 16KB] = 96 KB
  __shared__ __align__(16) unsigned short LDSu[49152];

  f32x4 acc[4][4] = {};
  bf16x8 a_[2][2], b0_[2][2], b1_[2][2];

  const int srow = t >> 3;                        // 0..63
  const int scol = ((t & 7) ^ (srow & 7)) * 8;    // pre-swizzled source col
  const unsigned short* gA = A + (long)(m0 + srow) * 4096 + scol;
  const unsigned short* gB = B + (long)(n0 + srow) * 4096 + scol;

  // prologue: tiles 0,1 (6 loads each); vmcnt(6) validates tile 0
  SH_A(0, 0, 0); SH_B(0, 0, 0); SH_B(0, 1, 0); SH_A(0, 1, 0);
  SH_A(1, 0, 1); SH_B(1, 0, 1); SH_B(1, 1, 1); SH_A(1, 1, 1);
  asm volatile("s_waitcnt vmcnt(6)" ::: "memory");
  __builtin_amdgcn_s_barrier();

  // 64 k-tiles: groups 0..61 stage tiles 2..63; groups 62,63 drain
  for (int g = 0; g < 31; g++) {
    GROUP_PS(0, 2 * g + 2);
    GROUP_PS(1, 2 * g + 3);
  }
  GROUP_PN(0, 0);
  GROUP_PN(1, -1);

  // epilogue (after full drain): Ot = acc / lsum[row]
  float linv[4][4];
  for (int i = 0; i < 4; i++)
    for (int r = 0; r < 4; r++)
      linv[i][r] = 1.f / lsum[z * NPIX + m0 + i * 64 + wr * 16 + fq * 4 + r];
  for (int i = 0; i < 4; i++) {
    int mg = m0 + i * 64 + wr * 16 + fq * 4;
    for (int j = 0; j < 4; j++) {
      int ng = n0 + j * 32 + wc * 16 + fr;
      for (int r = 0; r < 4; r++)
        C[z * SLAB + (long)(mg + r) * 512 + ng] = f2bf(acc[i][j][r] * linv[i][r]);
    }
  }
}
#undef SH_A
#undef SH_B
#undef READ_PA
#undef READ_PB
#undef MF_P
#undef PHP
#undef GROUP_PS
#undef GROUP_PN

// ---------------- generic bf16 gemm_bt (r6 core + XCD swizzle, r10-proven) ----------------
template <int XCDX, int OUTF32, int BIASM, bool RESID, bool SCALE, bool EXPSUM, bool ROWSCALE>
__global__ __launch_bounds__(256) void gemm_bt_k(
    const unsigned short* __restrict__ A, const unsigned short* __restrict__ B,
    void* __restrict__ Cv, const float* __restrict__ bias,
    const float* __restrict__ resid, float* __restrict__ lsum,
    int K, int lda, int ldb, int ldc,
    long sA, long sB, long sC, float scale) {
  int z = blockIdx.z;
  A += z * sA;
  B += z * sB;

  int bx = blockIdx.x, by = blockIdx.y;
  if (XCDX > 0) {
    int s = blockIdx.x + gridDim.x * blockIdx.y;
    int xcd = s & 7, idx = s >> 3;
    int rw = gridDim.x / XCDX;
    int rh = (gridDim.y * XCDX) >> 3;
    int rx0 = (xcd % XCDX) * rw, ry0 = (xcd / XCDX) * rh;
    bx = rx0 + idx % rw;
    by = ry0 + idx / rw;
  }
  const int n0 = bx * 128, m0 = by * 128;

  const int t = threadIdx.x;
  const int lane = t & 63, w = t >> 6;
  const int wr = w >> 1, wc = w & 1;

  __shared__ __align__(16) unsigned short As[128 * 64];
  __shared__ __align__(16) unsigned short Bs[128 * 64];

  f32x4 acc[4][4] = {};

  const int srow = t >> 3;
  const int scol = (((t & 7) ^ (srow & 7)) * 8);
  const unsigned short* ga = A + (long)(m0 + srow) * lda + scol;
  const unsigned short* gb = B + (long)(n0 + srow) * ldb + scol;
  char* lA = (char*)As + t * 16;
  char* lB = (char*)Bs + t * 16;
  const long stpa = (long)32 * lda;
  const long stpb = (long)32 * ldb;

  const int fr = lane & 15, fq = lane >> 4;
  const int chx = fr & 7;
  const unsigned short* rA = As + (wr * 64 + fr) * 64;
  const unsigned short* rB = Bs + (wc * 64 + fr) * 64;

  const int nkt = K >> 6;
  for (int kt = 0; kt < nkt; kt++) {
    const unsigned short* gak = ga + (long)kt * 64;
    const unsigned short* gbk = gb + (long)kt * 64;
    GLD16(gak, lA);
    GLD16(gak + stpa, lA + 4096);
    GLD16(gak + 2 * stpa, lA + 8192);
    GLD16(gak + 3 * stpa, lA + 12288);
    GLD16(gbk, lB);
    GLD16(gbk + stpb, lB + 4096);
    GLD16(gbk + 2 * stpb, lB + 8192);
    GLD16(gbk + 3 * stpb, lB + 12288);
    __syncthreads();
    for (int kk = 0; kk < 2; kk++) {
      const int offA = ((fq + kk * 4) ^ chx) * 8;
      bf16x8 af[4], bfr[4];
      for (int i = 0; i < 4; i++) af[i] = *(const bf16x8*)(rA + i * 1024 + offA);
      for (int i = 0; i < 4; i++) bfr[i] = *(const bf16x8*)(rB + i * 1024 + offA);
      for (int i = 0; i < 4; i++)
        for (int j = 0; j < 4; j++)
          acc[i][j] = __builtin_amdgcn_mfma_f32_16x16x32_bf16(af[i], bfr[j], acc[i][j], 0, 0, 0);
    }
    __syncthreads();
  }

  if (OUTF32) {
    float* Cf = (float*)Cv;
    for (int i = 0; i < 4; i++) {
      int mg = m0 + wr * 64 + i * 16 + fq * 4;
      for (int j = 0; j < 4; j++) {
        int ng = n0 + wc * 64 + j * 16 + fr;
        for (int r = 0; r < 4; r++) {
          float v = acc[i][j][r];
          if (SCALE) v *= scale;
          int m = mg + r;
          if (BIASM == 1) v += bias[m];
          else if (BIASM == 2) v += bias[ng];
          long off = z * sC + (long)m * ldc + ng;
          if (RESID) v += resid[off];
          Cf[off] = v;
        }
      }
    }
  } else {
    float linv[4][4];
    if (ROWSCALE) {
      for (int i = 0; i < 4; i++)
        for (int r = 0; r < 4; r++)
          linv[i][r] = 1.f / lsum[z * NPIX + m0 + wr * 64 + i * 16 + fq * 4 + r];
    }
    float rsum[4][4];
    if (EXPSUM) {
      for (int i = 0; i < 4; i++)
        for (int r = 0; r < 4; r++) rsum[i][r] = 0.f;
    }
    unsigned short* Cb = (unsigned short*)Cv;
    for (int i = 0; i < 4; i++) {
      int mg = m0 + wr * 64 + i * 16 + fq * 4;
      for (int j = 0; j < 4; j++) {
        int ng = n0 + wc * 64 + j * 16 + fr;
        for (int r = 0; r < 4; r++) {
          float v = acc[i][j][r];
          if (SCALE) v *= scale;
          if (BIASM == 1) v += bias[mg + r];
          else if (BIASM == 2) v += bias[ng];
          if (EXPSUM) { v = exp2f(v); rsum[i][r] += v; }
          if (ROWSCALE) v *= linv[i][r];
          Cb[z * sC + (long)(mg + r) * ldc + ng] = f2bf(v);
        }
      }
    }
    if (EXPSUM) {
      for (int i = 0; i < 4; i++)
        for (int r = 0; r < 4; r++) {
          float s = rsum[i][r];
          s += __shfl_xor(s, 1);
          s += __shfl_xor(s, 2);
          s += __shfl_xor(s, 4);
          s += __shfl_xor(s, 8);
          if (fr == 0)
            atomicAdd(&lsum[z * NPIX + m0 + wr * 64 + i * 16 + fq * 4 + r], s);
        }
    }
  }
}

extern "C" void kernel_launch(void* const* d_in, const int* in_sizes, int n_in,
                              void* d_out, int out_size, void* d_ws, size_t ws_size,
                              hipStream_t stream) {
  const float* x  = (const float*)d_in[0];
  const float* wq = (const float*)d_in[1];
  const float* bq = (const float*)d_in[2];
  const float* wk = (const float*)d_in[3];
  const float* bk = (const float*)d_in[4];
  const float* wv = (const float*)d_in[5];
  const float* bv = (const float*)d_in[6];
  const float* wp = (const float*)d_in[7];
  const float* bp = (const float*)d_in[8];

  char* ws = (char*)d_ws;
  const long SLAB = (long)NPIX * CCH;
  const long SLAB2 = (long)NPIX * 1024;
  const long SLABP = (long)NPIX * NPIX;

  float* stats = (float*)ws;
  float* bqk = (float*)(ws + (32l << 10));
  float* lsum = (float*)(ws + (64l << 10));
  unsigned short* wbf = (unsigned short*)(ws + (192l << 10));
  unsigned short* hnT = (unsigned short*)(ws + (192l << 10) + (1l << 21));
  unsigned short* QKt = hnT + 4 * SLAB;
  unsigned short* V   = QKt + 4 * SLAB2;
  unsigned short* Ot  = V + 4 * SLAB;
  unsigned short* S4  = Ot + 4 * SLAB;

  unsigned short* wv_bf = wbf + 2 * 262144;
  unsigned short* wp_bf = wbf + 3 * 262144;

  cast_weights_k<<<dim3(1024, 4, 1), 256, 0, stream>>>(wq, wk, wv, wp, wbf);
  bias_concat_k<<<dim3(4, 1, 1), 256, 0, stream>>>(bq, bk, bqk);
  zero_l_k<<<dim3(16, 1, 1), 256, 0, stream>>>(lsum);
  stats_k<<<dim3(NB * CCH, 1, 1), 256, 0, stream>>>(x, stats);
  norm_t_k<<<dim3(128, 16, 4), 256, 0, stream>>>(x, stats, hnT);

  // QKt[b][i][n] = hnT[b] . [wq;wk]^T + bqk
  gemm_bt_k<1, 0, 2, false, false, false, false><<<dim3(8, 32, 4), 256, 0, stream>>>(
      hnT, wbf, QKt, bqk, nullptr, nullptr, 512, 512, 512, 1024, SLAB, 0, SLAB2, 1.f);
  // V[b][o][j] = Wv . hnT[b]^T + bv
  gemm_bt_k<2, 0, 1, false, false, false, false><<<dim3(32, 4, 4), 256, 0, stream>>>(
      wv_bf, hnT, V, bv, nullptr, nullptr, 512, 512, 512, 4096, 0, SLAB, SLAB, 1.f);

  // scale = (1/sqrt(512)) * log2(e)
  const float isc2 = 0.06375871387551278f;
  // E = exp(Q.K^T/sqrt(C)) via 8-phase 256^2 kernel (r13)
  gemm8p_s_k<<<dim3(16, 16, 4), 512, 0, stream>>>(QKt, QKt + 512, S4, lsum, isc2);
  // Ot[b][i][c] = (E[b] . V[b]^T) / lsum[b][i] via 8-phase 256x128 K=4096 kernel
  gemm8p_pv_k<<<dim3(4, 16, 4), 512, 0, stream>>>(S4, V, Ot, lsum);
  // out[b][o][i] = x + Wp . Ot[b]^T + bp
  gemm_bt_k<2, 1, 1, true, false, false, false><<<dim3(32, 4, 4), 256, 0, stream>>>(
      wp_bf, Ot, d_out, bp, x, nullptr, 512, 512, 512, 4096, 0, SLAB, SLAB, 1.f);
}

// Round 16
// 279.344 us; speedup vs baseline: 2.2796x; 1.0528x over previous
//
#include <hip/hip_runtime.h>
#include <hip/hip_bf16.h>

typedef short bf16x8 __attribute__((ext_vector_type(8)));
typedef float f32x4 __attribute__((ext_vector_type(4)));

#define CCH 512
#define NPIX 4096
#define NB 4

__device__ inline unsigned short f2bf(float f) {
  union { __hip_bfloat16 h; unsigned short u; } cv;
  cv.h = __float2bfloat16(f);
  return cv.u;
}

#define GLD16(gp, lp) __builtin_amdgcn_global_load_lds( \
    (const __attribute__((address_space(1))) unsigned int*)(gp), \
    (__attribute__((address_space(3))) unsigned int*)(lp), 16, 0, 0)

// ---------------- weight fp32 -> bf16 cast ----------------
__global__ __launch_bounds__(256) void cast_weights_k(
    const float* __restrict__ w0, const float* __restrict__ w1,
    const float* __restrict__ w2, const float* __restrict__ w3,
    unsigned short* __restrict__ out) {
  int z = blockIdx.y;
  const float* src = (z == 0) ? w0 : (z == 1) ? w1 : (z == 2) ? w2 : w3;
  long i = (long)blockIdx.x * 256 + threadIdx.x;
  out[(long)z * CCH * CCH + i] = f2bf(src[i]);
}

// ---------------- concat bq,bk -> bqk[1024] ----------------
__global__ __launch_bounds__(256) void bias_concat_k(
    const float* __restrict__ bq, const float* __restrict__ bk,
    float* __restrict__ bqk) {
  int i = blockIdx.x * 256 + threadIdx.x;
  bqk[i] = (i < CCH) ? bq[i] : bk[i - CCH];
}

// ---------------- zero the softmax row-sum accumulator ----------------
__global__ __launch_bounds__(256) void zero_l_k(float* __restrict__ lsum) {
  int i = (blockIdx.x * 256 + threadIdx.x) * 4;
  *(float4*)(lsum + i) = make_float4(0.f, 0.f, 0.f, 0.f);
}

// ---------------- instance-norm stats: one block per (b,c) plane ----------------
__global__ __launch_bounds__(256) void stats_k(const float* __restrict__ x,
                                               float* __restrict__ stats) {
  long plane = blockIdx.x;
  const float4* p = (const float4*)(x + plane * NPIX);
  int t = threadIdx.x;
  float s = 0.f, q = 0.f;
  for (int c = 0; c < 4; c++) {
    float4 v = p[c * 256 + t];
    s += v.x + v.y + v.z + v.w;
    q += v.x * v.x + v.y * v.y + v.z * v.z + v.w * v.w;
  }
  for (int off = 32; off; off >>= 1) { s += __shfl_xor(s, off); q += __shfl_xor(q, off); }
  __shared__ float rs[4], rq[4];
  int w = t >> 6;
  if ((t & 63) == 0) { rs[w] = s; rq[w] = q; }
  __syncthreads();
  if (t == 0) {
    s = rs[0] + rs[1] + rs[2] + rs[3];
    q = rq[0] + rq[1] + rq[2] + rq[3];
    float mu = s * (1.f / NPIX);
    float var = q * (1.f / NPIX) - mu * mu;
    stats[2 * plane] = mu;
    stats[2 * plane + 1] = rsqrtf(var + 1e-5f);
  }
}

// ---------------- normalize + transpose: x[b][c][i] -> hnT[b][i][c] bf16 ----------------
__global__ __launch_bounds__(256) void norm_t_k(const float* __restrict__ x,
                                                const float* __restrict__ stats,
                                                unsigned short* __restrict__ hnT) {
  int b = blockIdx.z;
  int c0 = blockIdx.y * 32, i0 = blockIdx.x * 32;
  __shared__ float tile[32][33];
  int t = threadIdx.x;
  int il = t & 31, cl = t >> 5;  // cl in 0..7
  for (int r = 0; r < 4; r++) {
    int c = c0 + cl + r * 8;
    long pl = (long)b * CCH + c;
    float mu = stats[2 * pl], rsg = stats[2 * pl + 1];
    tile[cl + r * 8][il] = (x[pl * NPIX + i0 + il] - mu) * rsg;
  }
  __syncthreads();
  for (int r = 0; r < 4; r++) {
    int i = i0 + cl + r * 8;
    hnT[((long)b * NPIX + i) * CCH + c0 + il] = f2bf(tile[il][cl + r * 8]);
  }
}

// ================= 8-phase 256x256 S-kernel (r13 core + XCD region swizzle) ==
#define SH(sl, ha, h, kt) do {                                               \
    const unsigned short* g_ = ((ha) ? gB : gA) + (long)(kt) * 64 +          \
                               (long)(2 * (h)) * 65536;                      \
    char* l_ = (char*)LDSu + (sl) * 65536 + (ha) * 32768 + (2 * (h)) * 8192  \
               + t * 16;                                                     \
    GLD16(g_, l_);                                                           \
    GLD16(g_ + 65536, l_ + 8192);                                            \
  } while (0)

#define READ_A(sl, half) do {                                                \
    const unsigned short* sa_ = LDSu + (sl) * 32768;                         \
    _Pragma("unroll") for (int mm = 0; mm < 4; mm++) {                       \
      int row = ((half) * 4 + mm) * 32 + wr * 16 + fr;                       \
      a_[mm][0] = *(const bf16x8*)(sa_ + row * 64 + o0_);                    \
      a_[mm][1] = *(const bf16x8*)(sa_ + row * 64 + o1_);                    \
    }                                                                        \
  } while (0)

#define READ_B(sl, half, dst) do {                                           \
    const unsigned short* sb_ = LDSu + (sl) * 32768 + 16384;                 \
    _Pragma("unroll") for (int nn = 0; nn < 2; nn++) {                       \
      int row = ((half) * 2 + nn) * 64 + wc * 16 + fr;                       \
      dst[nn][0] = *(const bf16x8*)(sb_ + row * 64 + o0_);                   \
      dst[nn][1] = *(const bf16x8*)(sb_ + row * 64 + o1_);                   \
    }                                                                        \
  } while (0)

#define MF(qm, qn, bb)                                                       \
    _Pragma("unroll") for (int mm = 0; mm < 4; mm++)                         \
      _Pragma("unroll") for (int nn = 0; nn < 2; nn++) {                     \
        acc[(qm) * 4 + mm][(qn) * 2 + nn] =                                  \
            __builtin_amdgcn_mfma_f32_16x16x32_bf16(                         \
                a_[mm][0], bb[nn][0], acc[(qm) * 4 + mm][(qn) * 2 + nn],     \
                0, 0, 0);                                                    \
        acc[(qm) * 4 + mm][(qn) * 2 + nn] =                                  \
            __builtin_amdgcn_mfma_f32_16x16x32_bf16(                         \
                a_[mm][1], bb[nn][1], acc[(qm) * 4 + mm][(qn) * 2 + nn],     \
                0, 0, 0);                                                    \
      }

#define PHASE(VN, SSTMT, RSTMT, MSTMT) do {                                  \
    SSTMT;                                                                   \
    RSTMT;                                                                   \
    if ((VN) == 8) asm volatile("s_waitcnt vmcnt(8)" ::: "memory");          \
    else if ((VN) == 0) asm volatile("s_waitcnt vmcnt(0)" ::: "memory");     \
    __builtin_amdgcn_s_barrier();                                            \
    asm volatile("s_waitcnt lgkmcnt(0)" ::: "memory");                       \
    __builtin_amdgcn_sched_barrier(0);                                       \
    __builtin_amdgcn_s_setprio(1);                                           \
    MSTMT;                                                                   \
    __builtin_amdgcn_s_setprio(0);                                           \
    __builtin_amdgcn_sched_barrier(0);                                       \
    __builtin_amdgcn_s_barrier();                                            \
  } while (0)

#define GROUP_S(sl, tn)                                                      \
    PHASE(-1, (void)0, { READ_A(sl, 0); READ_B(sl, 0, b0_); }, MF(0, 0, b0_)); \
    PHASE(-1, { SH(sl, 0, 0, tn); SH(sl, 1, 0, tn); },                       \
          READ_B(sl, 1, b1_), MF(0, 1, b1_));                                \
    PHASE(-1, SH(sl, 1, 1, tn), READ_A(sl, 1), MF(1, 1, b1_));               \
    PHASE(8, SH(sl, 0, 1, tn), (void)0, MF(1, 0, b0_))

#define GROUP_N(sl, VN3)                                                     \
    PHASE(-1, (void)0, { READ_A(sl, 0); READ_B(sl, 0, b0_); }, MF(0, 0, b0_)); \
    PHASE(-1, (void)0, READ_B(sl, 1, b1_), MF(0, 1, b1_));                   \
    PHASE(-1, (void)0, READ_A(sl, 1), MF(1, 1, b1_));                        \
    PHASE(VN3, (void)0, (void)0, MF(1, 0, b0_))

__global__ __launch_bounds__(512, 2) void gemm8p_s_k(
    const unsigned short* __restrict__ A,   // Q rows [i][1024]
    const unsigned short* __restrict__ B,   // K rows (A + 512)
    unsigned short* __restrict__ C,         // E bf16 [i][4096]
    float* __restrict__ lsum, float scale) {
  const int z = blockIdx.z;
  const long SLAB2 = (long)NPIX * 1024;
  const long SLABP = (long)NPIX * NPIX;
  A += z * SLAB2;
  B += z * SLAB2;
  // XCD region swizzle (16x16 grid, 256%8==0 per z -> phase stable):
  // xcd c owns the 8x4 region at (rx0,ry0) = ((c&1)*8, (c>>1)*4).
  int s = blockIdx.x + 16 * blockIdx.y;
  int xcd = s & 7, idx = s >> 3;          // idx in [0,32)
  int bx = (xcd & 1) * 8 + (idx & 7);
  int by = (xcd >> 1) * 4 + (idx >> 3);
  const int m0 = by * 256, n0 = bx * 256;
  const int t = threadIdx.x;
  const int lane = t & 63, w = t >> 6;
  const int wr = w >> 2, wc = w & 3;
  const int fr = lane & 15, fq = lane >> 4;
  const int chx = fr & 7;
  const int o0_ = (fq ^ chx) * 8, o1_ = ((fq + 4) ^ chx) * 8;

  __shared__ __align__(16) unsigned short LDSu[2 * 32768];  // 128 KB

  f32x4 acc[8][4] = {};
  bf16x8 a_[4][2], b0_[2][2], b1_[2][2];

  const int srow = t >> 3;                        // 0..63
  const int scol = ((t & 7) ^ (srow & 7)) * 8;    // pre-swizzled source col
  const unsigned short* gA = A + (long)(m0 + srow) * 1024 + scol;
  const unsigned short* gB = B + (long)(n0 + srow) * 1024 + scol;

  SH(0, 0, 0, 0); SH(0, 1, 0, 0); SH(0, 0, 1, 0); SH(0, 1, 1, 0);
  SH(1, 0, 0, 1); SH(1, 1, 0, 1); SH(1, 0, 1, 1); SH(1, 1, 1, 1);
  asm volatile("s_waitcnt vmcnt(8)" ::: "memory");
  __builtin_amdgcn_s_barrier();

  GROUP_S(0, 2); GROUP_S(1, 3);
  GROUP_S(0, 4); GROUP_S(1, 5);
  GROUP_S(0, 6); GROUP_S(1, 7);
  GROUP_N(0, 0);
  GROUP_N(1, -1);

  float rsum[8][4];
  for (int i = 0; i < 8; i++)
    for (int r = 0; r < 4; r++) rsum[i][r] = 0.f;
  for (int i = 0; i < 8; i++) {
    int mg = m0 + i * 32 + wr * 16 + fq * 4;
    for (int j = 0; j < 4; j++) {
      int ng = n0 + j * 64 + wc * 16 + fr;
      for (int r = 0; r < 4; r++) {
        float v = exp2f(acc[i][j][r] * scale);
        rsum[i][r] += v;
        C[z * SLABP + (long)(mg + r) * 4096 + ng] = f2bf(v);
      }
    }
  }
  for (int i = 0; i < 8; i++)
    for (int r = 0; r < 4; r++) {
      float s2 = rsum[i][r];
      s2 += __shfl_xor(s2, 1);
      s2 += __shfl_xor(s2, 2);
      s2 += __shfl_xor(s2, 4);
      s2 += __shfl_xor(s2, 8);
      if (fr == 0)
        atomicAdd(&lsum[z * NPIX + m0 + i * 32 + wr * 16 + fq * 4 + r], s2);
    }
}
#undef SH
#undef READ_A
#undef READ_B
#undef MF
#undef PHASE
#undef GROUP_S
#undef GROUP_N

// ============ 8-phase 256x128 PV kernel: Ot = (E . V^T) / lsum ==============
// r15 core + SAME-E-SLAB XCD GROUPING: the 4 blocks (bx=0..3) that read the
// same 256-row E slab (by) are placed on the SAME XCD -> the slab is fetched
// from HBM once into that L2 instead of 4x across 4 XCDs (E HBM 512->128 MB).
// Mapping: hw slot s = blockIdx.x + 4*blockIdx.y (64/z, 64%8==0); xcd = s&7;
// by = 2*xcd + (idx>>2), bx = idx&3 (idx = s>>3 in [0,8)) — bijective.
#define SH_A(sl, h, kk) do {                                                 \
    const unsigned short* g_ = gA + (long)(kk) * 64 + (long)(2 * (h)) * 262144; \
    char* l_ = (char*)LDSu + (sl) * 32768 + (2 * (h)) * 8192 + t * 16;       \
    GLD16(g_, l_);                                                           \
    GLD16(g_ + 262144, l_ + 8192);                                           \
  } while (0)

#define SH_B(sl, h, kk) do {                                                 \
    const unsigned short* g_ = gB + (long)(kk) * 64 + (long)(h) * 262144;    \
    char* l_ = (char*)LDSu + 65536 + (sl) * 16384 + (h) * 8192 + t * 16;     \
    GLD16(g_, l_);                                                           \
  } while (0)

#define READ_PA(sl, half) do {                                               \
    const unsigned short* sa_ = LDSu + (sl) * 16384;                         \
    _Pragma("unroll") for (int mm = 0; mm < 2; mm++) {                       \
      int row = ((half) * 2 + mm) * 64 + wr * 16 + fr;                       \
      a_[mm][0] = *(const bf16x8*)(sa_ + row * 64 + o0_);                    \
      a_[mm][1] = *(const bf16x8*)(sa_ + row * 64 + o1_);                    \
    }                                                                        \
  } while (0)

#define READ_PB(sl, half, dst) do {                                          \
    const unsigned short* sb_ = LDSu + 32768 + (sl) * 8192;                  \
    _Pragma("unroll") for (int nn = 0; nn < 2; nn++) {                       \
      int row = ((half) * 2 + nn) * 32 + wc * 16 + fr;                       \
      dst[nn][0] = *(const bf16x8*)(sb_ + row * 64 + o0_);                   \
      dst[nn][1] = *(const bf16x8*)(sb_ + row * 64 + o1_);                   \
    }                                                                        \
  } while (0)

#define MF_P(qm, qn, bb)                                                     \
    _Pragma("unroll") for (int mm = 0; mm < 2; mm++)                         \
      _Pragma("unroll") for (int nn = 0; nn < 2; nn++) {                     \
        acc[(qm) * 2 + mm][(qn) * 2 + nn] =                                  \
            __builtin_amdgcn_mfma_f32_16x16x32_bf16(                         \
                a_[mm][0], bb[nn][0], acc[(qm) * 2 + mm][(qn) * 2 + nn],     \
                0, 0, 0);                                                    \
        acc[(qm) * 2 + mm][(qn) * 2 + nn] =                                  \
            __builtin_amdgcn_mfma_f32_16x16x32_bf16(                         \
                a_[mm][1], bb[nn][1], acc[(qm) * 2 + mm][(qn) * 2 + nn],     \
                0, 0, 0);                                                    \
      }

#define PHP(VN, SSTMT, RSTMT, MSTMT) do {                                    \
    SSTMT;                                                                   \
    RSTMT;                                                                   \
    if ((VN) == 6) asm volatile("s_waitcnt vmcnt(6)" ::: "memory");          \
    else if ((VN) == 0) asm volatile("s_waitcnt vmcnt(0)" ::: "memory");     \
    __builtin_amdgcn_s_barrier();                                            \
    asm volatile("s_waitcnt lgkmcnt(0)" ::: "memory");                       \
    __builtin_amdgcn_sched_barrier(0);                                       \
    __builtin_amdgcn_s_setprio(1);                                           \
    MSTMT;                                                                   \
    __builtin_amdgcn_s_setprio(0);                                           \
    __builtin_amdgcn_sched_barrier(0);                                       \
    __builtin_amdgcn_s_barrier();                                            \
  } while (0)

#define GROUP_PS(sl, kk)                                                     \
    PHP(-1, (void)0, { READ_PA(sl, 0); READ_PB(sl, 0, b0_); }, MF_P(0, 0, b0_)); \
    PHP(-1, { SH_A(sl, 0, kk); SH_B(sl, 0, kk); },                           \
        READ_PB(sl, 1, b1_), MF_P(0, 1, b1_));                               \
    PHP(-1, SH_B(sl, 1, kk), READ_PA(sl, 1), MF_P(1, 1, b1_));               \
    PHP(6, SH_A(sl, 1, kk), (void)0, MF_P(1, 0, b0_))

#define GROUP_PN(sl, VN3)                                                    \
    PHP(-1, (void)0, { READ_PA(sl, 0); READ_PB(sl, 0, b0_); }, MF_P(0, 0, b0_)); \
    PHP(-1, (void)0, READ_PB(sl, 1, b1_), MF_P(0, 1, b1_));                  \
    PHP(-1, (void)0, READ_PA(sl, 1), MF_P(1, 1, b1_));                       \
    PHP(VN3, (void)0, (void)0, MF_P(1, 0, b0_))

__global__ __launch_bounds__(512, 2) void gemm8p_pv_k(
    const unsigned short* __restrict__ A,   // E [i][4096]
    const unsigned short* __restrict__ B,   // V [o][4096]
    unsigned short* __restrict__ C,         // Ot bf16 [i][512]
    const float* __restrict__ lsum) {
  const int z = blockIdx.z;
  const long SLAB = (long)NPIX * CCH;
  const long SLABP = (long)NPIX * NPIX;
  A += z * SLABP;
  B += z * SLAB;
  // same-E-slab XCD grouping (see header comment)
  int s = blockIdx.x + 4 * blockIdx.y;   // [0,64)
  int xcd = s & 7, idx = s >> 3;          // idx [0,8)
  int by = xcd * 2 + (idx >> 2);          // [0,16)
  int bx = idx & 3;                       // [0,4)
  const int m0 = by * 256, n0 = bx * 128;
  const int t = threadIdx.x;
  const int lane = t & 63, w = t >> 6;
  const int wr = w >> 1, wc = w & 1;   // 4(M) x 2(N) wave grid
  const int fr = lane & 15, fq = lane >> 4;
  const int chx = fr & 7;
  const int o0_ = (fq ^ chx) * 8, o1_ = ((fq + 4) ^ chx) * 8;

  // [A slot0 32KB][A slot1 32KB][B slot0 16KB][B slot1 16KB] = 96 KB
  __shared__ __align__(16) unsigned short LDSu[49152];

  f32x4 acc[4][4] = {};
  bf16x8 a_[2][2], b0_[2][2], b1_[2][2];

  const int srow = t >> 3;                        // 0..63
  const int scol = ((t & 7) ^ (srow & 7)) * 8;    // pre-swizzled source col
  const unsigned short* gA = A + (long)(m0 + srow) * 4096 + scol;
  const unsigned short* gB = B + (long)(n0 + srow) * 4096 + scol;

  // prologue: tiles 0,1 (6 loads each); vmcnt(6) validates tile 0
  SH_A(0, 0, 0); SH_B(0, 0, 0); SH_B(0, 1, 0); SH_A(0, 1, 0);
  SH_A(1, 0, 1); SH_B(1, 0, 1); SH_B(1, 1, 1); SH_A(1, 1, 1);
  asm volatile("s_waitcnt vmcnt(6)" ::: "memory");
  __builtin_amdgcn_s_barrier();

  // 64 k-tiles: groups 0..61 stage tiles 2..63; groups 62,63 drain
  for (int g = 0; g < 31; g++) {
    GROUP_PS(0, 2 * g + 2);
    GROUP_PS(1, 2 * g + 3);
  }
  GROUP_PN(0, 0);
  GROUP_PN(1, -1);

  // epilogue (after full drain): Ot = acc / lsum[row]
  float linv[4][4];
  for (int i = 0; i < 4; i++)
    for (int r = 0; r < 4; r++)
      linv[i][r] = 1.f / lsum[z * NPIX + m0 + i * 64 + wr * 16 + fq * 4 + r];
  for (int i = 0; i < 4; i++) {
    int mg = m0 + i * 64 + wr * 16 + fq * 4;
    for (int j = 0; j < 4; j++) {
      int ng = n0 + j * 32 + wc * 16 + fr;
      for (int r = 0; r < 4; r++)
        C[z * SLAB + (long)(mg + r) * 512 + ng] = f2bf(acc[i][j][r] * linv[i][r]);
    }
  }
}
#undef SH_A
#undef SH_B
#undef READ_PA
#undef READ_PB
#undef MF_P
#undef PHP
#undef GROUP_PS
#undef GROUP_PN

// ---------------- generic bf16 gemm_bt (r6 core + XCD swizzle, r10-proven) ----------------
template <int XCDX, int OUTF32, int BIASM, bool RESID, bool SCALE, bool EXPSUM, bool ROWSCALE>
__global__ __launch_bounds__(256) void gemm_bt_k(
    const unsigned short* __restrict__ A, const unsigned short* __restrict__ B,
    void* __restrict__ Cv, const float* __restrict__ bias,
    const float* __restrict__ resid, float* __restrict__ lsum,
    int K, int lda, int ldb, int ldc,
    long sA, long sB, long sC, float scale) {
  int z = blockIdx.z;
  A += z * sA;
  B += z * sB;

  int bx = blockIdx.x, by = blockIdx.y;
  if (XCDX > 0) {
    int s = blockIdx.x + gridDim.x * blockIdx.y;
    int xcd = s & 7, idx = s >> 3;
    int rw = gridDim.x / XCDX;
    int rh = (gridDim.y * XCDX) >> 3;
    int rx0 = (xcd % XCDX) * rw, ry0 = (xcd / XCDX) * rh;
    bx = rx0 + idx % rw;
    by = ry0 + idx / rw;
  }
  const int n0 = bx * 128, m0 = by * 128;

  const int t = threadIdx.x;
  const int lane = t & 63, w = t >> 6;
  const int wr = w >> 1, wc = w & 1;

  __shared__ __align__(16) unsigned short As[128 * 64];
  __shared__ __align__(16) unsigned short Bs[128 * 64];

  f32x4 acc[4][4] = {};

  const int srow = t >> 3;
  const int scol = (((t & 7) ^ (srow & 7)) * 8);
  const unsigned short* ga = A + (long)(m0 + srow) * lda + scol;
  const unsigned short* gb = B + (long)(n0 + srow) * ldb + scol;
  char* lA = (char*)As + t * 16;
  char* lB = (char*)Bs + t * 16;
  const long stpa = (long)32 * lda;
  const long stpb = (long)32 * ldb;

  const int fr = lane & 15, fq = lane >> 4;
  const int chx = fr & 7;
  const unsigned short* rA = As + (wr * 64 + fr) * 64;
  const unsigned short* rB = Bs + (wc * 64 + fr) * 64;

  const int nkt = K >> 6;
  for (int kt = 0; kt < nkt; kt++) {
    const unsigned short* gak = ga + (long)kt * 64;
    const unsigned short* gbk = gb + (long)kt * 64;
    GLD16(gak, lA);
    GLD16(gak + stpa, lA + 4096);
    GLD16(gak + 2 * stpa, lA + 8192);
    GLD16(gak + 3 * stpa, lA + 12288);
    GLD16(gbk, lB);
    GLD16(gbk + stpb, lB + 4096);
    GLD16(gbk + 2 * stpb, lB + 8192);
    GLD16(gbk + 3 * stpb, lB + 12288);
    __syncthreads();
    for (int kk = 0; kk < 2; kk++) {
      const int offA = ((fq + kk * 4) ^ chx) * 8;
      bf16x8 af[4], bfr[4];
      for (int i = 0; i < 4; i++) af[i] = *(const bf16x8*)(rA + i * 1024 + offA);
      for (int i = 0; i < 4; i++) bfr[i] = *(const bf16x8*)(rB + i * 1024 + offA);
      for (int i = 0; i < 4; i++)
        for (int j = 0; j < 4; j++)
          acc[i][j] = __builtin_amdgcn_mfma_f32_16x16x32_bf16(af[i], bfr[j], acc[i][j], 0, 0, 0);
    }
    __syncthreads();
  }

  if (OUTF32) {
    float* Cf = (float*)Cv;
    for (int i = 0; i < 4; i++) {
      int mg = m0 + wr * 64 + i * 16 + fq * 4;
      for (int j = 0; j < 4; j++) {
        int ng = n0 + wc * 64 + j * 16 + fr;
        for (int r = 0; r < 4; r++) {
          float v = acc[i][j][r];
          if (SCALE) v *= scale;
          int m = mg + r;
          if (BIASM == 1) v += bias[m];
          else if (BIASM == 2) v += bias[ng];
          long off = z * sC + (long)m * ldc + ng;
          if (RESID) v += resid[off];
          Cf[off] = v;
        }
      }
    }
  } else {
    float linv[4][4];
    if (ROWSCALE) {
      for (int i = 0; i < 4; i++)
        for (int r = 0; r < 4; r++)
          linv[i][r] = 1.f / lsum[z * NPIX + m0 + wr * 64 + i * 16 + fq * 4 + r];
    }
    float rsum[4][4];
    if (EXPSUM) {
      for (int i = 0; i < 4; i++)
        for (int r = 0; r < 4; r++) rsum[i][r] = 0.f;
    }
    unsigned short* Cb = (unsigned short*)Cv;
    for (int i = 0; i < 4; i++) {
      int mg = m0 + wr * 64 + i * 16 + fq * 4;
      for (int j = 0; j < 4; j++) {
        int ng = n0 + wc * 64 + j * 16 + fr;
        for (int r = 0; r < 4; r++) {
          float v = acc[i][j][r];
          if (SCALE) v *= scale;
          if (BIASM == 1) v += bias[mg + r];
          else if (BIASM == 2) v += bias[ng];
          if (EXPSUM) { v = exp2f(v); rsum[i][r] += v; }
          if (ROWSCALE) v *= linv[i][r];
          Cb[z * sC + (long)(mg + r) * ldc + ng] = f2bf(v);
        }
      }
    }
    if (EXPSUM) {
      for (int i = 0; i < 4; i++)
        for (int r = 0; r < 4; r++) {
          float s = rsum[i][r];
          s += __shfl_xor(s, 1);
          s += __shfl_xor(s, 2);
          s += __shfl_xor(s, 4);
          s += __shfl_xor(s, 8);
          if (fr == 0)
            atomicAdd(&lsum[z * NPIX + m0 + wr * 64 + i * 16 + fq * 4 + r], s);
        }
    }
  }
}

extern "C" void kernel_launch(void* const* d_in, const int* in_sizes, int n_in,
                              void* d_out, int out_size, void* d_ws, size_t ws_size,
                              hipStream_t stream) {
  const float* x  = (const float*)d_in[0];
  const float* wq = (const float*)d_in[1];
  const float* bq = (const float*)d_in[2];
  const float* wk = (const float*)d_in[3];
  const float* bk = (const float*)d_in[4];
  const float* wv = (const float*)d_in[5];
  const float* bv = (const float*)d_in[6];
  const float* wp = (const float*)d_in[7];
  const float* bp = (const float*)d_in[8];

  char* ws = (char*)d_ws;
  const long SLAB = (long)NPIX * CCH;
  const long SLAB2 = (long)NPIX * 1024;
  const long SLABP = (long)NPIX * NPIX;

  float* stats = (float*)ws;
  float* bqk = (float*)(ws + (32l << 10));
  float* lsum = (float*)(ws + (64l << 10));
  unsigned short* wbf = (unsigned short*)(ws + (192l << 10));
  unsigned short* hnT = (unsigned short*)(ws + (192l << 10) + (1l << 21));
  unsigned short* QKt = hnT + 4 * SLAB;
  unsigned short* V   = QKt + 4 * SLAB2;
  unsigned short* Ot  = V + 4 * SLAB;
  unsigned short* S4  = Ot + 4 * SLAB;

  unsigned short* wv_bf = wbf + 2 * 262144;
  unsigned short* wp_bf = wbf + 3 * 262144;

  cast_weights_k<<<dim3(1024, 4, 1), 256, 0, stream>>>(wq, wk, wv, wp, wbf);
  bias_concat_k<<<dim3(4, 1, 1), 256, 0, stream>>>(bq, bk, bqk);
  zero_l_k<<<dim3(16, 1, 1), 256, 0, stream>>>(lsum);
  stats_k<<<dim3(NB * CCH, 1, 1), 256, 0, stream>>>(x, stats);
  norm_t_k<<<dim3(128, 16, 4), 256, 0, stream>>>(x, stats, hnT);

  // QKt[b][i][n] = hnT[b] . [wq;wk]^T + bqk
  gemm_bt_k<1, 0, 2, false, false, false, false><<<dim3(8, 32, 4), 256, 0, stream>>>(
      hnT, wbf, QKt, bqk, nullptr, nullptr, 512, 512, 512, 1024, SLAB, 0, SLAB2, 1.f);
  // V[b][o][j] = Wv . hnT[b]^T + bv
  gemm_bt_k<2, 0, 1, false, false, false, false><<<dim3(32, 4, 4), 256, 0, stream>>>(
      wv_bf, hnT, V, bv, nullptr, nullptr, 512, 512, 512, 4096, 0, SLAB, SLAB, 1.f);

  // scale = (1/sqrt(512)) * log2(e)
  const float isc2 = 0.06375871387551278f;
  // E = exp(Q.K^T/sqrt(C)) via 8-phase 256^2 kernel (+XCD region swizzle)
  gemm8p_s_k<<<dim3(16, 16, 4), 512, 0, stream>>>(QKt, QKt + 512, S4, lsum, isc2);
  // Ot[b][i][c] = (E[b] . V[b]^T) / lsum[b][i] (+same-E-slab XCD grouping)
  gemm8p_pv_k<<<dim3(4, 16, 4), 512, 0, stream>>>(S4, V, Ot, lsum);
  // out[b][o][i] = x + Wp . Ot[b]^T + bp
  gemm_bt_k<2, 1, 1, true, false, false, false><<<dim3(32, 4, 4), 256, 0, stream>>>(
      wp_bf, Ot, d_out, bp, x, nullptr, 512, 512, 512, 4096, 0, SLAB, SLAB, 1.f);
}